// Round 6
// baseline (104.428 us; speedup 1.0000x reference)
//
#include <hip/hip_runtime.h>
#include <hip/hip_cooperative_groups.h>

namespace cg = cooperative_groups;

#define TRAIN_ROIS 256
#define POS_QUOTA 25          // int(0.1 * 256)
#define POS_THR 0.5f
#define NEG_THR 0.02f
#define EPS 1e-8f
#define G_MAX 32
#define B_MAX 16
#define SEG 1024              // proposals per segment (= block size)

// IoU with arithmetic mirroring the reference exactly (left-assoc products,
// (v1+v2)-inter+eps denominator). Pure mul/sub/div/max: no FMA-contraction
// ambiguity, so recomputation is bit-identical across phases.
__device__ __forceinline__ float iou3d(const float* __restrict__ g,
                                       const float* __restrict__ b) {
    float lo0 = fmaxf(g[0], b[0]);
    float lo1 = fmaxf(g[1], b[1]);
    float lo2 = fmaxf(g[2], b[2]);
    float hi0 = fminf(g[3], b[3]);
    float hi1 = fminf(g[4], b[4]);
    float hi2 = fminf(g[5], b[5]);
    float d0 = fmaxf(hi0 - lo0, 0.0f);
    float d1 = fmaxf(hi1 - lo1, 0.0f);
    float d2 = fmaxf(hi2 - lo2, 0.0f);
    float inter = (d0 * d1) * d2;
    float v1 = ((g[3] - g[0]) * (g[4] - g[1])) * (g[5] - g[2]);
    float v2 = ((b[3] - b[0]) * (b[4] - b[1])) * (b[5] - b[2]);
    return inter / (((v1 + v2) - inter) + EPS);
}

// One cooperative kernel, three phases separated by grid.sync():
//  A (blocks 0..NSEG-1): per-proposal pos/neg tie bitmasks + per-segment
//    counts stored transposed (gcntSegT[slot][seg]); full-mask (all-G tie,
//    the common iou==0 neg case) counted separately.
//  B (all blocks, 4 strided (seg,it) tasks each): per-task parallel prefix
//    recompute from count rows -> off/need/startRank; single ballot pass
//    places matches in first-k flat order. seg==0 task writes totals.
//  C (blocks 0..1): emit rois/deltas/labels/tag/ridx for all B*256 slots.
__launch_bounds__(1024, 4)
__global__ void fusedKernel(const float* __restrict__ props, const int* __restrict__ bidx,
                            const float* __restrict__ gtb, const int* __restrict__ glab,
                            unsigned int* __restrict__ posBits, unsigned int* __restrict__ negBits,
                            int* __restrict__ gcntSegT, int* __restrict__ gcntFullSegT,
                            int* __restrict__ totals, int* __restrict__ orders,
                            float* __restrict__ out,
                            int P, int B, int G, int ITS, int NSEG) {
    cg::grid_group gg = cg::this_grid();

    __shared__ int sc[B_MAX * 2 * G_MAX];
    __shared__ int scFull[B_MAX * 2];
    __shared__ float s_gtb[B_MAX * G_MAX * 6];
    __shared__ int s_rowTot[G_MAX], s_rowPre[G_MAX];
    __shared__ int s_fullTot, s_fullPre;
    __shared__ int s_srk[G_MAX], s_off[G_MAX], s_need[G_MAX];
    __shared__ unsigned int s_active;
    __shared__ int s_wcnt[16][G_MAX];

    int blk = blockIdx.x;
    int tid = threadIdx.x;
    int lane = tid & 63, wid = tid >> 6;
    int nSlots = ITS * G_MAX;

    // ---------------- Phase A ----------------
    if (blk < NSEG) {
        int seg = blk;
        int p = seg * SEG + tid;
        for (int t = tid; t < nSlots; t += blockDim.x) sc[t] = 0;
        if (tid < ITS) scFull[tid] = 0;
        for (int t = tid; t < B * G * 6; t += blockDim.x) s_gtb[t] = gtb[t];
        __syncthreads();

        if (p < P) {
            int i = bidx[p];
            const float2* pp = reinterpret_cast<const float2*>(props + (size_t)p * 6);
            float2 a0 = pp[0], a1 = pp[1], a2 = pp[2];
            float b[6] = {a0.x, a0.y, a1.x, a1.y, a2.x, a2.y};
            const float* gbase = s_gtb + i * G * 6;
            float iou[G_MAX];
            float m = -1e30f;
#pragma unroll
            for (int g = 0; g < G_MAX; ++g) {
                if (g < G) {
                    iou[g] = iou3d(gbase + g * 6, b);
                    m = fmaxf(m, iou[g]);
                } else {
                    iou[g] = -2.0f;
                }
            }
            unsigned int pb = 0, nb = 0;
            if (m >= POS_THR) {
#pragma unroll
                for (int g = 0; g < G_MAX; ++g)
                    if (iou[g] == m) pb |= 1u << g;
            } else if (m < NEG_THR) {  // m >= 0 always for in-image proposals
#pragma unroll
                for (int g = 0; g < G_MAX; ++g)
                    if (iou[g] == m) nb |= 1u << g;
            }
            posBits[p] = pb;
            negBits[p] = nb;
            unsigned int fullMask = (G >= 32) ? 0xFFFFFFFFu : ((1u << G) - 1u);
            if (pb) {
                if (pb == fullMask) atomicAdd(&scFull[i * 2 + 0], 1);
                else {
                    unsigned int t = pb;
                    while (t) { int g = __ffs(t) - 1; t &= t - 1; atomicAdd(&sc[(i * 2 + 0) * G_MAX + g], 1); }
                }
            }
            if (nb) {
                if (nb == fullMask) atomicAdd(&scFull[i * 2 + 1], 1);
                else {
                    unsigned int t = nb;
                    while (t) { int g = __ffs(t) - 1; t &= t - 1; atomicAdd(&sc[(i * 2 + 1) * G_MAX + g], 1); }
                }
            }
        }
        __syncthreads();
        for (int t = tid; t < nSlots; t += blockDim.x)
            gcntSegT[(size_t)t * NSEG + seg] = sc[t];
        if (tid < ITS) gcntFullSegT[(size_t)tid * NSEG + seg] = scFull[tid];
    }

    gg.sync();

    // ---------------- Phase B ----------------
    int nTask = NSEG * ITS;
    unsigned long long laneLt = (1ull << lane) - 1ull;
    for (int task = blk; task < nTask; task += gridDim.x) {
        int seg = task / ITS;
        int it = task - seg * ITS;   // == blk % ITS when ITS | gridDim.x
        int type = it & 1;
        int i = it >> 1;

        __syncthreads();   // protect shared reuse across tasks
        // stage 1: row sums (thread g: partial row; thread 32: full-mask row)
        if (tid < G_MAX) {
            const int* row = gcntSegT + (size_t)(it * G_MAX + tid) * NSEG;
            int tot = 0, pre = 0;
            if ((NSEG & 3) == 0) {
#pragma unroll 8
                for (int s = 0; s < NSEG; s += 4) {
                    int4 v = *reinterpret_cast<const int4*>(row + s);
                    int q = v.x + v.y + v.z + v.w;
                    tot += q;
                    if (s + 4 <= seg) pre += q;
                    else if (s < seg) {
                        if (s + 0 < seg) pre += v.x;
                        if (s + 1 < seg) pre += v.y;
                        if (s + 2 < seg) pre += v.z;
                    }
                }
            } else {
                for (int s = 0; s < NSEG; ++s) { int v = row[s]; tot += v; if (s < seg) pre += v; }
            }
            s_rowTot[tid] = tot;
            s_rowPre[tid] = pre;
        } else if (tid == G_MAX) {
            const int* frow = gcntFullSegT + (size_t)it * NSEG;
            int tot = 0, pre = 0;
            if ((NSEG & 3) == 0) {
#pragma unroll 8
                for (int s = 0; s < NSEG; s += 4) {
                    int4 v = *reinterpret_cast<const int4*>(frow + s);
                    int q = v.x + v.y + v.z + v.w;
                    tot += q;
                    if (s + 4 <= seg) pre += q;
                    else if (s < seg) {
                        if (s + 0 < seg) pre += v.x;
                        if (s + 1 < seg) pre += v.y;
                        if (s + 2 < seg) pre += v.z;
                    }
                }
            } else {
                for (int s = 0; s < NSEG; ++s) { int v = frow[s]; tot += v; if (s < seg) pre += v; }
            }
            s_fullTot = tot;
            s_fullPre = pre;
        }
        __syncthreads();
        // stage 2: prefix over g -> off/need/startRank; active mask; totals
        if (tid < G_MAX) {
            int fullTot = s_fullTot, fullPre = s_fullPre;
            int base = 0;
            for (int gg2 = 0; gg2 < tid; ++gg2)
                base += (gg2 < G) ? (s_rowTot[gg2] + fullTot) : 0;
            int totalG = (tid < G) ? (s_rowTot[tid] + fullTot) : 0;
            int cap = type ? TRAIN_ROIS : POS_QUOTA;
            int nd = cap - base;
            if (nd < 0) nd = 0;
            if (nd > totalG) nd = totalG;
            int srk = s_rowPre[tid] + fullPre;
            s_off[tid] = base;
            s_need[tid] = nd;
            s_srk[tid] = srk;
            if (seg == 0 && tid == G - 1) {
                int tot = base + totalG;
                totals[it] = tot > TRAIN_ROIS ? TRAIN_ROIS : tot;
            }
            unsigned long long bal = __ballot(srk < nd);
            if (tid == 0) s_active = (unsigned int)bal;
        }
        __syncthreads();
        unsigned int active = s_active;
        if (!active) continue;   // uniform per block

        int p = seg * SEG + tid;
        unsigned int mask = 0;
        if (p < P && bidx[p] == i)
            mask = (type ? negBits : posBits)[p] & active;

        unsigned int am = active;
        while (am) {
            int g = __ffs(am) - 1; am &= am - 1;
            unsigned long long bal = __ballot((mask >> g) & 1u);
            if (lane == 0) s_wcnt[wid][g] = __popcll(bal);
        }
        __syncthreads();
        if (tid < G_MAX && ((active >> tid) & 1u)) {
            int run = 0;
#pragma unroll
            for (int w = 0; w < 16; ++w) {
                int c = s_wcnt[w][tid];
                s_wcnt[w][tid] = run;
                run += c;
            }
        }
        __syncthreads();
        am = active;
        while (am) {
            int g = __ffs(am) - 1; am &= am - 1;
            bool bit = (mask >> g) & 1u;
            unsigned long long bal = __ballot(bit);
            if (bit) {
                int r = s_srk[g] + s_wcnt[wid][g] + __popcll(bal & laneLt);
                if (r < s_need[g]) orders[it * TRAIN_ROIS + s_off[g] + r] = g * P + p;
            }
        }
    }

    gg.sync();

    // ---------------- Phase C ----------------
    int nRows = B * TRAIN_ROIS;
    for (int rrow = blk * blockDim.x + tid; rrow < nRows; rrow += gridDim.x * blockDim.x) {
        int i = rrow / TRAIN_ROIS;
        int s = rrow - i * TRAIN_ROIS;
        int pos_total = totals[2 * i + 0];
        int neg_total = totals[2 * i + 1];
        int pos_num = pos_total < POS_QUOTA ? pos_total : POS_QUOTA;
        int rem = TRAIN_ROIS - pos_num;
        int neg_num = neg_total < rem ? neg_total : rem;
        bool is_pos = s < pos_num;
        bool valid = s < pos_num + neg_num;
        int t = s - pos_num;
        t = t < 0 ? 0 : t;
        int idx = 0;
        if (valid)
            idx = is_pos ? orders[(2 * i + 0) * TRAIN_ROIS + s]
                         : orders[(2 * i + 1) * TRAIN_ROIS + t];
        int g = idx / P;
        int p = idx - g * P;
        float b[6], gt[6];
#pragma unroll
        for (int k = 0; k < 6; ++k) {
            b[k] = props[(size_t)p * 6 + k];
            gt[k] = gtb[((size_t)i * G + g) * 6 + k];
        }
        float vf = valid ? 1.0f : 0.0f;
        int row = i * TRAIN_ROIS + s;
        float* o_rois = out;
        float* o_del = out + (size_t)B * TRAIN_ROIS * 6;
        float* o_lab = o_del + (size_t)B * TRAIN_ROIS * 6;
        float* o_tag = o_lab + (size_t)B * TRAIN_ROIS;
        float* o_ridx = o_tag + (size_t)B * TRAIN_ROIS;
#pragma unroll
        for (int k = 0; k < 6; ++k) o_rois[row * 6 + k] = b[k] * vf;
        float sz0 = b[3] - b[0], sz1 = b[4] - b[1], sz2 = b[5] - b[2];
        float c0 = (b[0] + b[3]) * 0.5f, c1 = (b[1] + b[4]) * 0.5f, c2 = (b[2] + b[5]) * 0.5f;
        float gs0 = gt[3] - gt[0], gs1 = gt[4] - gt[1], gs2 = gt[5] - gt[2];
        float gc0 = (gt[0] + gt[3]) * 0.5f, gc1 = (gt[1] + gt[4]) * 0.5f, gc2 = (gt[2] + gt[5]) * 0.5f;
        float d[6];
        d[0] = (gc0 - c0) / sz0;
        d[1] = (gc1 - c1) / sz1;
        d[2] = (gc2 - c2) / sz2;
        d[3] = logf(gs0 / sz0);
        d[4] = logf(gs1 / sz1);
        d[5] = logf(gs2 / sz2);
#pragma unroll
        for (int k = 0; k < 6; ++k) o_del[row * 6 + k] = d[k] * vf;
        int lab = is_pos ? glab[i * G + g] : 0;
        o_lab[row] = (float)(valid ? lab : 0);
        o_tag[row] = is_pos ? 1.0f : (valid ? -1.0f : 0.0f);
        o_ridx[row] = valid ? (float)i : -1.0f;
    }
}

extern "C" void kernel_launch(void* const* d_in, const int* in_sizes, int n_in,
                              void* d_out, int out_size, void* d_ws, size_t ws_size,
                              hipStream_t stream) {
    const float* props = (const float*)d_in[0];
    const int* bidx = (const int*)d_in[1];
    const float* gtb = (const float*)d_in[2];
    const int* glab = (const int*)d_in[3];
    int P = in_sizes[1];                       // 65536
    int B = out_size / (TRAIN_ROIS * 15);      // 6+6+1+1+1 per slot -> 8
    int G = in_sizes[3] / B;                   // 32
    int ITS = B * 2;                           // 16
    int NSEG = (P + SEG - 1) / SEG;            // 64
    int nSlots = ITS * G_MAX;                  // 512

    unsigned int* posBits = (unsigned int*)d_ws;            // [P]
    unsigned int* negBits = posBits + (size_t)P;            // [P]
    int* orders = (int*)(negBits + (size_t)P);              // [ITS][256]
    int* gcntSegT = orders + ITS * TRAIN_ROIS;              // [nSlots][NSEG]
    int* gcntFullSegT = gcntSegT + (size_t)nSlots * NSEG;   // [ITS][NSEG]
    int* totals = gcntFullSegT + (size_t)ITS * NSEG;        // [ITS]

    float* outf = (float*)d_out;
    int grid = NSEG * ITS / 4;                 // 256 blocks (1 per CU)

    void* args[] = {
        (void*)&props, (void*)&bidx, (void*)&gtb, (void*)&glab,
        (void*)&posBits, (void*)&negBits,
        (void*)&gcntSegT, (void*)&gcntFullSegT,
        (void*)&totals, (void*)&orders, (void*)&outf,
        (void*)&P, (void*)&B, (void*)&G, (void*)&ITS, (void*)&NSEG,
    };
    hipLaunchCooperativeKernel((void*)fusedKernel, dim3(grid), dim3(SEG),
                               args, 0, stream);
}

// Round 7
// 46.461 us; speedup vs baseline: 2.2477x; 2.2477x over previous
//
#include <hip/hip_runtime.h>

#define TRAIN_ROIS 256
#define POS_QUOTA 25          // int(0.1 * 256)
#define POS_THR 0.5f
#define NEG_THR 0.02f
#define EPS 1e-8f
#define G_MAX 32
#define B_MAX 16
#define SEG 1024              // proposals per segment (= block size)

// IoU with arithmetic mirroring the reference exactly (left-assoc products,
// (v1+v2)-inter+eps denominator). Pure mul/sub/div/max: no FMA-contraction
// ambiguity, so recomputation is bit-identical across kernels.
__device__ __forceinline__ float iou3d(const float* __restrict__ g,
                                       const float* __restrict__ b) {
    float lo0 = fmaxf(g[0], b[0]);
    float lo1 = fmaxf(g[1], b[1]);
    float lo2 = fmaxf(g[2], b[2]);
    float hi0 = fminf(g[3], b[3]);
    float hi1 = fminf(g[4], b[4]);
    float hi2 = fminf(g[5], b[5]);
    float d0 = fmaxf(hi0 - lo0, 0.0f);
    float d1 = fmaxf(hi1 - lo1, 0.0f);
    float d2 = fmaxf(hi2 - lo2, 0.0f);
    float inter = (d0 * d1) * d2;
    float v1 = ((g[3] - g[0]) * (g[4] - g[1])) * (g[5] - g[2]);
    float v2 = ((b[3] - b[0]) * (b[4] - b[1])) * (b[5] - b[2]);
    return inter / (((v1 + v2) - inter) + EPS);
}

// Emit one valid output row (vf=1). out layout: rois[B*256*6] | deltas[B*256*6]
// | labels[B*256] | tag[B*256] | ridx[B*256], all float32.
__device__ __forceinline__ void emitRow(float* __restrict__ out,
                                        const float* __restrict__ props,
                                        const float* __restrict__ gtb,
                                        const int* __restrict__ glab,
                                        int i, int s, int p, int g, bool is_pos,
                                        int B, int G) {
    float b[6], gt[6];
#pragma unroll
    for (int k = 0; k < 6; ++k) {
        b[k] = props[(size_t)p * 6 + k];
        gt[k] = gtb[((size_t)i * G + g) * 6 + k];
    }
    int row = i * TRAIN_ROIS + s;
    float* o_rois = out;
    float* o_del = out + (size_t)B * TRAIN_ROIS * 6;
    float* o_lab = o_del + (size_t)B * TRAIN_ROIS * 6;
    float* o_tag = o_lab + (size_t)B * TRAIN_ROIS;
    float* o_ridx = o_tag + (size_t)B * TRAIN_ROIS;
#pragma unroll
    for (int k = 0; k < 6; ++k) o_rois[row * 6 + k] = b[k];
    float sz0 = b[3] - b[0], sz1 = b[4] - b[1], sz2 = b[5] - b[2];
    float c0 = (b[0] + b[3]) * 0.5f, c1 = (b[1] + b[4]) * 0.5f, c2 = (b[2] + b[5]) * 0.5f;
    float gs0 = gt[3] - gt[0], gs1 = gt[4] - gt[1], gs2 = gt[5] - gt[2];
    float gc0 = (gt[0] + gt[3]) * 0.5f, gc1 = (gt[1] + gt[4]) * 0.5f, gc2 = (gt[2] + gt[5]) * 0.5f;
    o_del[row * 6 + 0] = (gc0 - c0) / sz0;
    o_del[row * 6 + 1] = (gc1 - c1) / sz1;
    o_del[row * 6 + 2] = (gc2 - c2) / sz2;
    o_del[row * 6 + 3] = logf(gs0 / sz0);
    o_del[row * 6 + 4] = logf(gs1 / sz1);
    o_del[row * 6 + 5] = logf(gs2 / sz2);
    o_lab[row] = is_pos ? (float)glab[i * G + g] : 0.0f;
    o_tag[row] = is_pos ? 1.0f : -1.0f;
    o_ridx[row] = (float)i;
}

// Phase A: one thread per proposal (block = one 1024-p segment). Computes the
// pos/neg tie bitmask and PER-SEGMENT counts, stored TRANSPOSED
// (gcntSegT[slot][seg], slot = it*32+g) so placeEmit reads contiguous rows.
// Full-mask (all-G tie, the common iou==0 neg case) counted separately.
__launch_bounds__(1024)
__global__ void phaseA(const float* __restrict__ props, const int* __restrict__ bidx,
                       const float* __restrict__ gtb,
                       unsigned int* __restrict__ posBits, unsigned int* __restrict__ negBits,
                       int* __restrict__ gcntSegT, int* __restrict__ gcntFullSegT,
                       int P, int B, int G, int ITS, int NSEG) {
    __shared__ int sc[B_MAX * 2 * G_MAX];
    __shared__ int scFull[B_MAX * 2];
    __shared__ float s_gtb[B_MAX * G_MAX * 6];
    int tid = threadIdx.x;
    int seg = blockIdx.x;
    int p = seg * SEG + tid;
    int nSlots = ITS * G_MAX;
    for (int t = tid; t < nSlots; t += blockDim.x) sc[t] = 0;
    if (tid < ITS) scFull[tid] = 0;
    for (int t = tid; t < B * G * 6; t += blockDim.x) s_gtb[t] = gtb[t];
    __syncthreads();

    if (p < P) {
        int i = bidx[p];
        const float2* pp = reinterpret_cast<const float2*>(props + (size_t)p * 6);
        float2 a0 = pp[0], a1 = pp[1], a2 = pp[2];
        float b[6] = {a0.x, a0.y, a1.x, a1.y, a2.x, a2.y};
        const float* gbase = s_gtb + i * G * 6;
        float iou[G_MAX];
        float m = -1e30f;
#pragma unroll
        for (int g = 0; g < G_MAX; ++g) {
            if (g < G) {
                iou[g] = iou3d(gbase + g * 6, b);
                m = fmaxf(m, iou[g]);
            } else {
                iou[g] = -2.0f;
            }
        }
        unsigned int pb = 0, nb = 0;
        if (m >= POS_THR) {
#pragma unroll
            for (int g = 0; g < G_MAX; ++g)
                if (iou[g] == m) pb |= 1u << g;
        } else if (m < NEG_THR) {  // m >= 0 always for in-image proposals
#pragma unroll
            for (int g = 0; g < G_MAX; ++g)
                if (iou[g] == m) nb |= 1u << g;
        }
        posBits[p] = pb;
        negBits[p] = nb;
        unsigned int fullMask = (G >= 32) ? 0xFFFFFFFFu : ((1u << G) - 1u);
        if (pb) {
            if (pb == fullMask) atomicAdd(&scFull[i * 2 + 0], 1);
            else {
                unsigned int t = pb;
                while (t) { int g = __ffs(t) - 1; t &= t - 1; atomicAdd(&sc[(i * 2 + 0) * G_MAX + g], 1); }
            }
        }
        if (nb) {
            if (nb == fullMask) atomicAdd(&scFull[i * 2 + 1], 1);
            else {
                unsigned int t = nb;
                while (t) { int g = __ffs(t) - 1; t &= t - 1; atomicAdd(&sc[(i * 2 + 1) * G_MAX + g], 1); }
            }
        }
    }
    __syncthreads();
    for (int t = tid; t < nSlots; t += blockDim.x)
        gcntSegT[(size_t)t * NSEG + seg] = sc[t];
    if (tid < ITS) gcntFullSegT[(size_t)tid * NSEG + seg] = scFull[tid];
}

// Place+emit: one block per (segment, it). Recomputes its own prefix from the
// count rows (threads 0..31 own-rows, 32 own-full; neg blocks additionally
// threads 64..96 sum the image's POS rows to get pos_num). Then a single
// ballot pass places this segment's matches and writes the 15 output floats
// directly at the final slot. The (seg==0, neg) block of each image also
// constant-fills the invalid tail [valid_num, 256).
__launch_bounds__(1024)
__global__ void placeEmit(const float* __restrict__ props, const int* __restrict__ bidx,
                          const float* __restrict__ gtb, const int* __restrict__ glab,
                          const unsigned int* __restrict__ posBits,
                          const unsigned int* __restrict__ negBits,
                          const int* __restrict__ gcntSegT, const int* __restrict__ gcntFullSegT,
                          float* __restrict__ out,
                          int P, int B, int G, int ITS, int NSEG) {
    int blk = blockIdx.x;
    int seg = blk / ITS;
    int it = blk - seg * ITS;
    int type = it & 1;
    int i = it >> 1;

    __shared__ int s_rowTot[G_MAX], s_rowPre[G_MAX];
    __shared__ int s_fullTot, s_fullPre;
    __shared__ int s_posPart[G_MAX];
    __shared__ int s_posFull;
    __shared__ int s_posNum, s_slotEnd;
    __shared__ int s_srk[G_MAX], s_off[G_MAX], s_need[G_MAX];
    __shared__ unsigned int s_active;
    __shared__ int s_wcnt[16][G_MAX];

    int tid = threadIdx.x, lane = tid & 63, wid = tid >> 6;

    // stage 1: parallel row sums (all contiguous 64-int rows, int4 loads)
    if (tid < G_MAX) {
        const int* row = gcntSegT + (size_t)(it * G_MAX + tid) * NSEG;
        int tot = 0, pre = 0;
#pragma unroll 8
        for (int s = 0; s < NSEG; s += 4) {
            int4 v = *reinterpret_cast<const int4*>(row + s);
            int q = v.x + v.y + v.z + v.w;
            tot += q;
            if (s + 4 <= seg) pre += q;
            else if (s < seg) {
                pre += v.x;
                if (s + 1 < seg) pre += v.y;
                if (s + 2 < seg) pre += v.z;
            }
        }
        s_rowTot[tid] = tot;
        s_rowPre[tid] = pre;
    } else if (tid == G_MAX) {
        const int* frow = gcntFullSegT + (size_t)it * NSEG;
        int tot = 0, pre = 0;
#pragma unroll 8
        for (int s = 0; s < NSEG; s += 4) {
            int4 v = *reinterpret_cast<const int4*>(frow + s);
            int q = v.x + v.y + v.z + v.w;
            tot += q;
            if (s + 4 <= seg) pre += q;
            else if (s < seg) {
                pre += v.x;
                if (s + 1 < seg) pre += v.y;
                if (s + 2 < seg) pre += v.z;
            }
        }
        s_fullTot = tot;
        s_fullPre = pre;
    } else if (type && tid >= 64 && tid < 64 + G_MAX) {
        int g = tid - 64;
        const int* row = gcntSegT + (size_t)((it - 1) * G_MAX + g) * NSEG;
        int tot = 0;
#pragma unroll 8
        for (int s = 0; s < NSEG; s += 4) {
            int4 v = *reinterpret_cast<const int4*>(row + s);
            tot += v.x + v.y + v.z + v.w;
        }
        s_posPart[g] = tot;
    } else if (type && tid == 64 + G_MAX) {
        const int* frow = gcntFullSegT + (size_t)(it - 1) * NSEG;
        int tot = 0;
#pragma unroll 8
        for (int s = 0; s < NSEG; s += 4) {
            int4 v = *reinterpret_cast<const int4*>(frow + s);
            tot += v.x + v.y + v.z + v.w;
        }
        s_posFull = tot;
    }
    __syncthreads();

    // stage 2a: pos_num for this image
    if (tid == 0) {
        int pt = 0;
        if (type) {
            for (int g = 0; g < G; ++g) pt += s_posPart[g];
            pt += G * s_posFull;
        } else {
            for (int g = 0; g < G; ++g) pt += s_rowTot[g];
            pt += G * s_fullTot;
        }
        s_posNum = pt < POS_QUOTA ? pt : POS_QUOTA;
    }
    __syncthreads();
    int posNum = s_posNum;
    int cap = type ? (TRAIN_ROIS - posNum) : POS_QUOTA;
    int slotBase = type ? posNum : 0;

    // stage 2b: prefix over g -> off/need/startRank; active mask; slotEnd
    if (tid < G_MAX) {
        int fullTot = s_fullTot, fullPre = s_fullPre;
        int base = 0;
        for (int gg = 0; gg < tid && gg < G; ++gg) base += s_rowTot[gg] + fullTot;
        int totalG = (tid < G) ? (s_rowTot[tid] + fullTot) : 0;
        int nd = cap - base;
        if (nd < 0) nd = 0;
        if (nd > totalG) nd = totalG;
        int srk = s_rowPre[tid] + fullPre;
        s_off[tid] = base;
        s_need[tid] = nd;
        s_srk[tid] = srk;
        if (type && tid == G - 1) {
            int negTotal = base + totalG;
            int negNum = cap < negTotal ? cap : negTotal;
            s_slotEnd = posNum + negNum;
        }
        unsigned long long bal = __ballot(srk < nd);
        if (tid == 0) s_active = (unsigned int)bal;
    }
    __syncthreads();

    // constant-fill the invalid tail (one designated block per image)
    if (type && seg == 0) {
        int slotEnd = s_slotEnd;
        float* o_rois = out;
        float* o_del = out + (size_t)B * TRAIN_ROIS * 6;
        float* o_lab = o_del + (size_t)B * TRAIN_ROIS * 6;
        float* o_tag = o_lab + (size_t)B * TRAIN_ROIS;
        float* o_ridx = o_tag + (size_t)B * TRAIN_ROIS;
        for (int s = slotEnd + tid; s < TRAIN_ROIS; s += blockDim.x) {
            int row = i * TRAIN_ROIS + s;
#pragma unroll
            for (int k = 0; k < 6; ++k) {
                o_rois[row * 6 + k] = 0.0f;
                o_del[row * 6 + k] = 0.0f;
            }
            o_lab[row] = 0.0f;
            o_tag[row] = 0.0f;
            o_ridx[row] = -1.0f;
        }
    }

    unsigned int active = s_active;
    if (!active) return;

    int p = seg * SEG + tid;
    unsigned int mask = 0;
    if (p < P && bidx[p] == i)
        mask = (type ? negBits : posBits)[p] & active;

    // per-wave counts for active g's
    unsigned int am = active;
    while (am) {
        int g = __ffs(am) - 1; am &= am - 1;
        unsigned long long bal = __ballot((mask >> g) & 1u);
        if (lane == 0) s_wcnt[wid][g] = __popcll(bal);
    }
    __syncthreads();
    // exclusive prefix across the 16 waves (thread g handles bucket g)
    if (tid < G_MAX && ((active >> tid) & 1u)) {
        int run = 0;
#pragma unroll
        for (int w = 0; w < 16; ++w) {
            int c = s_wcnt[w][tid];
            s_wcnt[w][tid] = run;
            run += c;
        }
    }
    __syncthreads();
    // placement + direct output emit
    unsigned long long laneLt = (1ull << lane) - 1ull;
    am = active;
    while (am) {
        int g = __ffs(am) - 1; am &= am - 1;
        bool bit = (mask >> g) & 1u;
        unsigned long long bal = __ballot(bit);
        if (bit) {
            int r = s_srk[g] + s_wcnt[wid][g] + __popcll(bal & laneLt);
            if (r < s_need[g])
                emitRow(out, props, gtb, glab, i, slotBase + s_off[g] + r, p, g,
                        type == 0, B, G);
        }
    }
}

extern "C" void kernel_launch(void* const* d_in, const int* in_sizes, int n_in,
                              void* d_out, int out_size, void* d_ws, size_t ws_size,
                              hipStream_t stream) {
    const float* props = (const float*)d_in[0];
    const int* bidx = (const int*)d_in[1];
    const float* gtb = (const float*)d_in[2];
    const int* glab = (const int*)d_in[3];
    int P = in_sizes[1];                       // 65536
    int B = out_size / (TRAIN_ROIS * 15);      // 6+6+1+1+1 per slot -> 8
    int G = in_sizes[3] / B;                   // 32
    int ITS = B * 2;                           // 16
    int NSEG = (P + SEG - 1) / SEG;            // 64
    int nSlots = ITS * G_MAX;                  // 512

    unsigned int* posBits = (unsigned int*)d_ws;            // [P]
    unsigned int* negBits = posBits + (size_t)P;            // [P]
    int* gcntSegT = (int*)(negBits + (size_t)P);            // [nSlots][NSEG]
    int* gcntFullSegT = gcntSegT + (size_t)nSlots * NSEG;   // [ITS][NSEG]

    phaseA<<<NSEG, SEG, 0, stream>>>(props, bidx, gtb, posBits, negBits,
                                     gcntSegT, gcntFullSegT, P, B, G, ITS, NSEG);
    placeEmit<<<NSEG * ITS, SEG, 0, stream>>>(props, bidx, gtb, glab,
                                              posBits, negBits,
                                              gcntSegT, gcntFullSegT,
                                              (float*)d_out, P, B, G, ITS, NSEG);
}

// Round 8
// 43.796 us; speedup vs baseline: 2.3844x; 1.0609x over previous
//
#include <hip/hip_runtime.h>

#define TRAIN_ROIS 256
#define POS_QUOTA 25          // int(0.1 * 256)
#define POS_THR 0.5f
#define NEG_THR 0.02f
#define EPS 1e-8f
#define G_MAX 32
#define B_MAX 16
#define SEG 1024              // place segment (= place block size)
#define SEG_A 256             // phaseA quarter-segment (= phaseA block size)
#define GT_STRIDE 194         // 6*G_MAX+2: even (float2-aligned) and i*194%32=2i
                              // -> images land on disjoint bank pairs (conflict-free)
#define VOL_STRIDE 33         // (i*33+g)%32 = (i+g)%32 -> bank-spread volumes

// Phase A: one thread per proposal, block = one 256-p quarter-segment
// (256 blocks -> all CUs, 4x the LDS bandwidth of 64 big blocks).
// gt boxes staged in LDS with bank-spread padding; per-gt volumes precomputed
// (stride-33), per-proposal volume hoisted out of the g-loop. IoU arithmetic
// keeps the reference's exact left-assoc expressions (bit-identical to R1-R7).
// Counts stored transposed: gcntSegT[slot][quarter], slot = it*32+g.
__launch_bounds__(SEG_A)
__global__ void phaseA(const float* __restrict__ props, const int* __restrict__ bidx,
                       const float* __restrict__ gtb,
                       unsigned int* __restrict__ posBits, unsigned int* __restrict__ negBits,
                       int* __restrict__ gcntSegT, int* __restrict__ gcntFullSegT,
                       int P, int B, int G, int ITS, int NSEG4) {
    __shared__ int sc[B_MAX * 2 * G_MAX];
    __shared__ int scFull[B_MAX * 2];
    __shared__ float s_gtb[B_MAX * GT_STRIDE];
    __shared__ float s_gvol[B_MAX * VOL_STRIDE];
    int tid = threadIdx.x;
    int q = blockIdx.x;
    int p = q * SEG_A + tid;
    int nSlots = ITS * G_MAX;
    for (int t = tid; t < nSlots; t += SEG_A) sc[t] = 0;
    if (tid < ITS) scFull[tid] = 0;
    for (int i = 0; i < B; ++i)
        for (int j = tid; j < G * 6; j += SEG_A)
            s_gtb[i * GT_STRIDE + j] = gtb[i * G * 6 + j];
    for (int i = 0; i < B; ++i)
        for (int g = tid; g < G; g += SEG_A) {
            const float* gp = gtb + ((size_t)i * G + g) * 6;
            s_gvol[i * VOL_STRIDE + g] = ((gp[3] - gp[0]) * (gp[4] - gp[1])) * (gp[5] - gp[2]);
        }
    __syncthreads();

    if (p < P) {
        int i = bidx[p];
        const float2* pp = reinterpret_cast<const float2*>(props + (size_t)p * 6);
        float2 a0 = pp[0], a1 = pp[1], a2 = pp[2];
        float b0 = a0.x, b1 = a0.y, b2 = a1.x, b3 = a1.y, b4 = a2.x, b5 = a2.y;
        float v2 = ((b3 - b0) * (b4 - b1)) * (b5 - b2);
        const float* gbase = s_gtb + i * GT_STRIDE;
        const float* vbase = s_gvol + i * VOL_STRIDE;
        float iou[G_MAX];
        float m = -1e30f;
#pragma unroll
        for (int g = 0; g < G_MAX; ++g) {
            if (g < G) {
                const float* gp = gbase + g * 6;
                float2 q0 = *reinterpret_cast<const float2*>(gp);
                float2 q1 = *reinterpret_cast<const float2*>(gp + 2);
                float2 q2 = *reinterpret_cast<const float2*>(gp + 4);
                float lo0 = fmaxf(q0.x, b0);
                float lo1 = fmaxf(q0.y, b1);
                float lo2 = fmaxf(q1.x, b2);
                float hi0 = fminf(q1.y, b3);
                float hi1 = fminf(q2.x, b4);
                float hi2 = fminf(q2.y, b5);
                float d0 = fmaxf(hi0 - lo0, 0.0f);
                float d1 = fmaxf(hi1 - lo1, 0.0f);
                float d2 = fmaxf(hi2 - lo2, 0.0f);
                float inter = (d0 * d1) * d2;
                iou[g] = inter / (((vbase[g] + v2) - inter) + EPS);
                m = fmaxf(m, iou[g]);
            } else {
                iou[g] = -2.0f;
            }
        }
        unsigned int pb = 0, nb = 0;
        if (m >= POS_THR) {
#pragma unroll
            for (int g = 0; g < G_MAX; ++g)
                if (iou[g] == m) pb |= 1u << g;
        } else if (m < NEG_THR) {  // m >= 0 always for in-image proposals
#pragma unroll
            for (int g = 0; g < G_MAX; ++g)
                if (iou[g] == m) nb |= 1u << g;
        }
        posBits[p] = pb;
        negBits[p] = nb;
        unsigned int fullMask = (G >= 32) ? 0xFFFFFFFFu : ((1u << G) - 1u);
        if (pb) {
            if (pb == fullMask) atomicAdd(&scFull[i * 2 + 0], 1);
            else {
                unsigned int t = pb;
                while (t) { int g = __ffs(t) - 1; t &= t - 1; atomicAdd(&sc[(i * 2 + 0) * G_MAX + g], 1); }
            }
        }
        if (nb) {
            if (nb == fullMask) atomicAdd(&scFull[i * 2 + 1], 1);
            else {
                unsigned int t = nb;
                while (t) { int g = __ffs(t) - 1; t &= t - 1; atomicAdd(&sc[(i * 2 + 1) * G_MAX + g], 1); }
            }
        }
    }
    __syncthreads();
    for (int t = tid; t < nSlots; t += SEG_A)
        gcntSegT[(size_t)t * NSEG4 + q] = sc[t];
    if (tid < ITS) gcntFullSegT[(size_t)tid * NSEG4 + q] = scFull[tid];
}

// Place: one block per (segment, it). Threads 0..31 sum their g-row of
// NSEG4 quarter-counts (contiguous, int4); thread 32 the full-mask row.
// qe = seg*4 is int4-aligned, so the prefix split is exact. Then a 32-step
// prefix over g yields off/need/startRank; single ballot pass places this
// segment's matches in first-k flat order. (seg==0) block writes totals.
__launch_bounds__(1024)
__global__ void placeKernel(const unsigned int* __restrict__ posBits,
                            const unsigned int* __restrict__ negBits,
                            const int* __restrict__ bidx,
                            const int* __restrict__ gcntSegT, const int* __restrict__ gcntFullSegT,
                            int* __restrict__ orders, int* __restrict__ totals,
                            int P, int G, int ITS, int NSEG4) {
    int blk = blockIdx.x;
    int seg = blk / ITS;
    int it = blk - seg * ITS;
    int type = it & 1;
    int i = it >> 1;
    int qe = seg * (SEG / SEG_A);   // quarters strictly before this segment

    __shared__ int s_rowTot[G_MAX], s_rowPre[G_MAX];
    __shared__ int s_fullTot, s_fullPre;
    __shared__ int s_srk[G_MAX], s_off[G_MAX], s_need[G_MAX];
    __shared__ unsigned int s_active;
    __shared__ int s_wcnt[16][G_MAX];

    int tid = threadIdx.x, lane = tid & 63, wid = tid >> 6;

    if (tid < G_MAX) {
        const int* row = gcntSegT + (size_t)(it * G_MAX + tid) * NSEG4;
        int tot = 0, pre = 0;
#pragma unroll 8
        for (int s = 0; s < NSEG4; s += 4) {
            int4 v = *reinterpret_cast<const int4*>(row + s);
            int q = v.x + v.y + v.z + v.w;
            tot += q;
            if (s + 4 <= qe) pre += q;
        }
        s_rowTot[tid] = tot;
        s_rowPre[tid] = pre;
    } else if (tid == G_MAX) {
        const int* frow = gcntFullSegT + (size_t)it * NSEG4;
        int tot = 0, pre = 0;
#pragma unroll 8
        for (int s = 0; s < NSEG4; s += 4) {
            int4 v = *reinterpret_cast<const int4*>(frow + s);
            int q = v.x + v.y + v.z + v.w;
            tot += q;
            if (s + 4 <= qe) pre += q;
        }
        s_fullTot = tot;
        s_fullPre = pre;
    }
    __syncthreads();

    if (tid < G_MAX) {
        int fullTot = s_fullTot, fullPre = s_fullPre;
        int base = 0;
        for (int gg = 0; gg < tid && gg < G; ++gg) base += s_rowTot[gg] + fullTot;
        int totalG = (tid < G) ? (s_rowTot[tid] + fullTot) : 0;
        int cap = type ? TRAIN_ROIS : POS_QUOTA;
        int nd = cap - base;
        if (nd < 0) nd = 0;
        if (nd > totalG) nd = totalG;
        int srk = s_rowPre[tid] + fullPre;
        s_off[tid] = base;
        s_need[tid] = nd;
        s_srk[tid] = srk;
        if (seg == 0 && tid == G - 1) {
            int tot = base + totalG;
            totals[it] = tot > TRAIN_ROIS ? TRAIN_ROIS : tot;
        }
        unsigned long long bal = __ballot(srk < nd);
        if (tid == 0) s_active = (unsigned int)bal;
    }
    __syncthreads();
    unsigned int active = s_active;
    if (!active) return;

    int p = seg * SEG + tid;
    unsigned int mask = 0;
    if (p < P && bidx[p] == i)
        mask = (type ? negBits : posBits)[p] & active;

    // per-wave counts for active g's
    unsigned int am = active;
    while (am) {
        int g = __ffs(am) - 1; am &= am - 1;
        unsigned long long bal = __ballot((mask >> g) & 1u);
        if (lane == 0) s_wcnt[wid][g] = __popcll(bal);
    }
    __syncthreads();
    // exclusive prefix across the 16 waves (thread g handles bucket g)
    if (tid < G_MAX && ((active >> tid) & 1u)) {
        int run = 0;
#pragma unroll
        for (int w = 0; w < 16; ++w) {
            int c = s_wcnt[w][tid];
            s_wcnt[w][tid] = run;
            run += c;
        }
    }
    __syncthreads();
    // placement
    unsigned long long laneLt = (1ull << lane) - 1ull;
    am = active;
    while (am) {
        int g = __ffs(am) - 1; am &= am - 1;
        bool bit = (mask >> g) & 1u;
        unsigned long long bal = __ballot(bit);
        if (bit) {
            int r = s_srk[g] + s_wcnt[wid][g] + __popcll(bal & laneLt);
            if (r < s_need[g]) orders[it * TRAIN_ROIS + s_off[g] + r] = g * P + p;
        }
    }
}

// Phase C: emit all outputs. out layout: rois[B*256*6] | deltas[B*256*6] |
// labels[B*256] | tag[B*256] | ridx[B*256], all float32. Invalid slots force
// idx=0 (so `orders` needs no zero-init; outputs are masked by vf anyway).
__global__ void phaseC(const float* __restrict__ props, const float* __restrict__ gtb,
                       const int* __restrict__ glab,
                       const int* __restrict__ orders, const int* __restrict__ totals,
                       float* __restrict__ out, int P, int G, int B) {
    int i = blockIdx.x;
    int s = threadIdx.x;
    int pos_total = totals[2 * i + 0];
    int neg_total = totals[2 * i + 1];
    int pos_num = pos_total < POS_QUOTA ? pos_total : POS_QUOTA;
    int rem = TRAIN_ROIS - pos_num;
    int neg_num = neg_total < rem ? neg_total : rem;
    bool is_pos = s < pos_num;
    bool valid = s < pos_num + neg_num;
    int t = s - pos_num;
    t = t < 0 ? 0 : t;
    int idx = 0;
    if (valid)
        idx = is_pos ? orders[(2 * i + 0) * TRAIN_ROIS + s]
                     : orders[(2 * i + 1) * TRAIN_ROIS + t];
    int g = idx / P;
    int p = idx - g * P;
    float b[6], gt[6];
#pragma unroll
    for (int k = 0; k < 6; ++k) {
        b[k] = props[(size_t)p * 6 + k];
        gt[k] = gtb[((size_t)i * G + g) * 6 + k];
    }
    float vf = valid ? 1.0f : 0.0f;
    int row = i * TRAIN_ROIS + s;
    float* o_rois = out;
    float* o_del = out + (size_t)B * TRAIN_ROIS * 6;
    float* o_lab = o_del + (size_t)B * TRAIN_ROIS * 6;
    float* o_tag = o_lab + (size_t)B * TRAIN_ROIS;
    float* o_ridx = o_tag + (size_t)B * TRAIN_ROIS;
#pragma unroll
    for (int k = 0; k < 6; ++k) o_rois[row * 6 + k] = b[k] * vf;
    float sz0 = b[3] - b[0], sz1 = b[4] - b[1], sz2 = b[5] - b[2];
    float c0 = (b[0] + b[3]) * 0.5f, c1 = (b[1] + b[4]) * 0.5f, c2 = (b[2] + b[5]) * 0.5f;
    float gs0 = gt[3] - gt[0], gs1 = gt[4] - gt[1], gs2 = gt[5] - gt[2];
    float gc0 = (gt[0] + gt[3]) * 0.5f, gc1 = (gt[1] + gt[4]) * 0.5f, gc2 = (gt[2] + gt[5]) * 0.5f;
    float d[6];
    d[0] = (gc0 - c0) / sz0;
    d[1] = (gc1 - c1) / sz1;
    d[2] = (gc2 - c2) / sz2;
    d[3] = logf(gs0 / sz0);
    d[4] = logf(gs1 / sz1);
    d[5] = logf(gs2 / sz2);
#pragma unroll
    for (int k = 0; k < 6; ++k) o_del[row * 6 + k] = d[k] * vf;
    int lab = is_pos ? glab[i * G + g] : 0;
    o_lab[row] = (float)(valid ? lab : 0);
    o_tag[row] = is_pos ? 1.0f : (valid ? -1.0f : 0.0f);
    o_ridx[row] = valid ? (float)i : -1.0f;
}

extern "C" void kernel_launch(void* const* d_in, const int* in_sizes, int n_in,
                              void* d_out, int out_size, void* d_ws, size_t ws_size,
                              hipStream_t stream) {
    const float* props = (const float*)d_in[0];
    const int* bidx = (const int*)d_in[1];
    const float* gtb = (const float*)d_in[2];
    const int* glab = (const int*)d_in[3];
    int P = in_sizes[1];                       // 65536
    int B = out_size / (TRAIN_ROIS * 15);      // 6+6+1+1+1 per slot -> 8
    int G = in_sizes[3] / B;                   // 32
    int ITS = B * 2;                           // 16
    int NSEG = (P + SEG - 1) / SEG;            // 64   (place segments)
    int NSEG4 = (P + SEG_A - 1) / SEG_A;       // 256  (phaseA quarter-segments)
    int nSlots = ITS * G_MAX;                  // 512

    unsigned int* posBits = (unsigned int*)d_ws;            // [P]
    unsigned int* negBits = posBits + (size_t)P;            // [P]
    int* orders = (int*)(negBits + (size_t)P);              // [ITS][256]
    int* gcntSegT = orders + ITS * TRAIN_ROIS;              // [nSlots][NSEG4]
    int* gcntFullSegT = gcntSegT + (size_t)nSlots * NSEG4;  // [ITS][NSEG4]
    int* totals = gcntFullSegT + (size_t)ITS * NSEG4;       // [ITS]

    phaseA<<<NSEG4, SEG_A, 0, stream>>>(props, bidx, gtb, posBits, negBits,
                                        gcntSegT, gcntFullSegT, P, B, G, ITS, NSEG4);
    placeKernel<<<NSEG * ITS, SEG, 0, stream>>>(posBits, negBits, bidx,
                                                gcntSegT, gcntFullSegT,
                                                orders, totals, P, G, ITS, NSEG4);
    phaseC<<<B, TRAIN_ROIS, 0, stream>>>(props, gtb, glab, orders, totals,
                                         (float*)d_out, P, G, B);
}

// Round 9
// 35.204 us; speedup vs baseline: 2.9663x; 1.2440x over previous
//
#include <hip/hip_runtime.h>

#define TRAIN_ROIS 256
#define POS_QUOTA 25          // int(0.1 * 256)
#define POS_THR 0.5f
#define NEG_THR 0.02f
#define EPS 1e-8f
#define G_MAX 32
#define B_MAX 16
#define SEG 1024              // placeEmit segment (= its block size)
#define SEG_A 256             // phaseA quarter-segment (= its block size)
#define GT_STRIDE 194         // even (float2-aligned); i*194%32=2i -> disjoint bank pairs
#define VOL_STRIDE 33         // (i*33+g)%32=(i+g)%32 -> bank-spread volumes

// Phase A: one thread per proposal, block = 256-p quarter-segment (256 blocks
// -> all CUs). gt boxes staged bank-conflict-free in LDS; per-gt volumes
// precomputed. IoU keeps the reference's exact left-assoc arithmetic.
// Per-quarter counts stored transposed: gcntSegT[slot][quarter], slot=it*32+g;
// full-mask (all-G tie, the common iou==0 neg case) counted separately.
__launch_bounds__(SEG_A)
__global__ void phaseA(const float* __restrict__ props, const int* __restrict__ bidx,
                       const float* __restrict__ gtb,
                       unsigned int* __restrict__ posBits, unsigned int* __restrict__ negBits,
                       int* __restrict__ gcntSegT, int* __restrict__ gcntFullSegT,
                       int P, int B, int G, int ITS, int NSEG4) {
    __shared__ int sc[B_MAX * 2 * G_MAX];
    __shared__ int scFull[B_MAX * 2];
    __shared__ float s_gtb[B_MAX * GT_STRIDE];
    __shared__ float s_gvol[B_MAX * VOL_STRIDE];
    int tid = threadIdx.x;
    int q = blockIdx.x;
    int p = q * SEG_A + tid;
    int nSlots = ITS * G_MAX;
    for (int t = tid; t < nSlots; t += SEG_A) sc[t] = 0;
    if (tid < ITS) scFull[tid] = 0;
    for (int i = 0; i < B; ++i)
        for (int j = tid; j < G * 6; j += SEG_A)
            s_gtb[i * GT_STRIDE + j] = gtb[i * G * 6 + j];
    for (int i = 0; i < B; ++i)
        for (int g = tid; g < G; g += SEG_A) {
            const float* gp = gtb + ((size_t)i * G + g) * 6;
            s_gvol[i * VOL_STRIDE + g] = ((gp[3] - gp[0]) * (gp[4] - gp[1])) * (gp[5] - gp[2]);
        }
    __syncthreads();

    if (p < P) {
        int i = bidx[p];
        const float2* pp = reinterpret_cast<const float2*>(props + (size_t)p * 6);
        float2 a0 = pp[0], a1 = pp[1], a2 = pp[2];
        float b0 = a0.x, b1 = a0.y, b2 = a1.x, b3 = a1.y, b4 = a2.x, b5 = a2.y;
        float v2 = ((b3 - b0) * (b4 - b1)) * (b5 - b2);
        const float* gbase = s_gtb + i * GT_STRIDE;
        const float* vbase = s_gvol + i * VOL_STRIDE;
        float iou[G_MAX];
        float m = -1e30f;
#pragma unroll
        for (int g = 0; g < G_MAX; ++g) {
            if (g < G) {
                const float* gp = gbase + g * 6;
                float2 q0 = *reinterpret_cast<const float2*>(gp);
                float2 q1 = *reinterpret_cast<const float2*>(gp + 2);
                float2 q2 = *reinterpret_cast<const float2*>(gp + 4);
                float lo0 = fmaxf(q0.x, b0);
                float lo1 = fmaxf(q0.y, b1);
                float lo2 = fmaxf(q1.x, b2);
                float hi0 = fminf(q1.y, b3);
                float hi1 = fminf(q2.x, b4);
                float hi2 = fminf(q2.y, b5);
                float d0 = fmaxf(hi0 - lo0, 0.0f);
                float d1 = fmaxf(hi1 - lo1, 0.0f);
                float d2 = fmaxf(hi2 - lo2, 0.0f);
                float inter = (d0 * d1) * d2;
                iou[g] = inter / (((vbase[g] + v2) - inter) + EPS);
                m = fmaxf(m, iou[g]);
            } else {
                iou[g] = -2.0f;
            }
        }
        unsigned int pb = 0, nb = 0;
        if (m >= POS_THR) {
#pragma unroll
            for (int g = 0; g < G_MAX; ++g)
                if (iou[g] == m) pb |= 1u << g;
        } else if (m < NEG_THR) {  // m >= 0 always for in-image proposals
#pragma unroll
            for (int g = 0; g < G_MAX; ++g)
                if (iou[g] == m) nb |= 1u << g;
        }
        posBits[p] = pb;
        negBits[p] = nb;
        unsigned int fullMask = (G >= 32) ? 0xFFFFFFFFu : ((1u << G) - 1u);
        if (pb) {
            if (pb == fullMask) atomicAdd(&scFull[i * 2 + 0], 1);
            else {
                unsigned int t = pb;
                while (t) { int g = __ffs(t) - 1; t &= t - 1; atomicAdd(&sc[(i * 2 + 0) * G_MAX + g], 1); }
            }
        }
        if (nb) {
            if (nb == fullMask) atomicAdd(&scFull[i * 2 + 1], 1);
            else {
                unsigned int t = nb;
                while (t) { int g = __ffs(t) - 1; t &= t - 1; atomicAdd(&sc[(i * 2 + 1) * G_MAX + g], 1); }
            }
        }
    }
    __syncthreads();
    for (int t = tid; t < nSlots; t += SEG_A)
        gcntSegT[(size_t)t * NSEG4 + q] = sc[t];
    if (tid < ITS) gcntFullSegT[(size_t)tid * NSEG4 + q] = scFull[tid];
}

// Scan: one block per image (8 waves). Each wave handles one count row of
// NSEG4=256 ints (4/lane int4 + 6-step shfl_up wave scan) -> per-SEG exclusive
// prefixes (lane s = quarters 4s..4s+3) + row total. Thread 0 then does the
// capped 32-g prefix for pos (cap 25) and neg (cap 256-posNum) and writes
// off/need/posNum/slotEnd. Kills ALL redundant row-summing downstream.
__launch_bounds__(512)
__global__ void scanKernel(const int* __restrict__ gcntSegT, const int* __restrict__ gcntFullSegT,
                           int* __restrict__ srkSeg, int* __restrict__ fullSeg,
                           int* __restrict__ offA, int* __restrict__ needA,
                           int* __restrict__ posNumArr, int* __restrict__ slotEndArr,
                           int B, int G, int NSEG4, int NSEGP) {
    int i = blockIdx.x;
    int tid = threadIdx.x, lane = tid & 63, w = tid >> 6;
    __shared__ int s_rt[2 * G_MAX + 2];   // rows: pos g / posFull / neg g / negFull
    const int ROWS = 2 * G_MAX + 2;
    for (int r = w; r < ROWS; r += 8) {
        const int* src;
        int* dst;
        if (r < G_MAX) {
            int slot = (2 * i) * G_MAX + r;
            src = gcntSegT + (size_t)slot * NSEG4;
            dst = srkSeg + (size_t)slot * NSEGP;
        } else if (r == G_MAX) {
            src = gcntFullSegT + (size_t)(2 * i) * NSEG4;
            dst = fullSeg + (size_t)(2 * i) * NSEGP;
        } else if (r < 2 * G_MAX + 1) {
            int slot = (2 * i + 1) * G_MAX + (r - G_MAX - 1);
            src = gcntSegT + (size_t)slot * NSEG4;
            dst = srkSeg + (size_t)slot * NSEGP;
        } else {
            src = gcntFullSegT + (size_t)(2 * i + 1) * NSEG4;
            dst = fullSeg + (size_t)(2 * i + 1) * NSEGP;
        }
        int4 v = *reinterpret_cast<const int4*>(src + lane * 4);
        int s = v.x + v.y + v.z + v.w;
        int inc = s;
        for (int d = 1; d < 64; d <<= 1) {
            int t = __shfl_up(inc, d);
            if (lane >= d) inc += t;
        }
        dst[lane] = inc - s;              // exclusive prefix at quarter 4*lane
        if (lane == 63) s_rt[r] = inc;    // row total
    }
    __syncthreads();
    if (tid == 0) {
        int fullTot = s_rt[G_MAX];
        int base = 0;
        for (int g = 0; g < G; ++g) {
            int tg = s_rt[g] + fullTot;
            offA[(2 * i) * G_MAX + g] = base;
            int nd = POS_QUOTA - base;
            nd = nd < 0 ? 0 : (nd > tg ? tg : nd);
            needA[(2 * i) * G_MAX + g] = nd;
            base += tg;
        }
        int posNum = base < POS_QUOTA ? base : POS_QUOTA;
        posNumArr[i] = posNum;
        int fullTotN = s_rt[2 * G_MAX + 1];
        int capN = TRAIN_ROIS - posNum;
        int baseN = 0;
        for (int g = 0; g < G; ++g) {
            int tg = s_rt[G_MAX + 1 + g] + fullTotN;
            offA[(2 * i + 1) * G_MAX + g] = baseN;
            int nd = capN - baseN;
            nd = nd < 0 ? 0 : (nd > tg ? tg : nd);
            needA[(2 * i + 1) * G_MAX + g] = nd;
            baseN += tg;
        }
        int negNum = baseN < capN ? baseN : capN;
        slotEndArr[i] = posNum + negNum;
    }
}

// Emit one valid output row. out layout: rois[B*256*6] | deltas[B*256*6] |
// labels[B*256] | tag[B*256] | ridx[B*256], all float32.
__device__ __forceinline__ void emitRow(float* __restrict__ out,
                                        const float* __restrict__ props,
                                        const float* __restrict__ gtb,
                                        const int* __restrict__ glab,
                                        int i, int s, int p, int g, bool is_pos,
                                        int B, int G) {
    float b[6], gt[6];
#pragma unroll
    for (int k = 0; k < 6; ++k) {
        b[k] = props[(size_t)p * 6 + k];
        gt[k] = gtb[((size_t)i * G + g) * 6 + k];
    }
    int row = i * TRAIN_ROIS + s;
    float* o_rois = out;
    float* o_del = out + (size_t)B * TRAIN_ROIS * 6;
    float* o_lab = o_del + (size_t)B * TRAIN_ROIS * 6;
    float* o_tag = o_lab + (size_t)B * TRAIN_ROIS;
    float* o_ridx = o_tag + (size_t)B * TRAIN_ROIS;
#pragma unroll
    for (int k = 0; k < 6; ++k) o_rois[row * 6 + k] = b[k];
    float sz0 = b[3] - b[0], sz1 = b[4] - b[1], sz2 = b[5] - b[2];
    float c0 = (b[0] + b[3]) * 0.5f, c1 = (b[1] + b[4]) * 0.5f, c2 = (b[2] + b[5]) * 0.5f;
    float gs0 = gt[3] - gt[0], gs1 = gt[4] - gt[1], gs2 = gt[5] - gt[2];
    float gc0 = (gt[0] + gt[3]) * 0.5f, gc1 = (gt[1] + gt[4]) * 0.5f, gc2 = (gt[2] + gt[5]) * 0.5f;
    o_del[row * 6 + 0] = (gc0 - c0) / sz0;
    o_del[row * 6 + 1] = (gc1 - c1) / sz1;
    o_del[row * 6 + 2] = (gc2 - c2) / sz2;
    o_del[row * 6 + 3] = logf(gs0 / sz0);
    o_del[row * 6 + 4] = logf(gs1 / sz1);
    o_del[row * 6 + 5] = logf(gs2 / sz2);
    o_lab[row] = is_pos ? (float)glab[i * G + g] : 0.0f;
    o_tag[row] = is_pos ? 1.0f : -1.0f;
    o_ridx[row] = (float)i;
}

// Place+emit: one block per (segment, it). Reads ONLY precomputed scalars
// (srk at its seg boundary, off, need, posNum, slotEnd) — no row sums. Single
// ballot pass places this segment's matches in first-k flat order and writes
// the 15 output floats directly. (seg==0, neg) block fills the invalid tail.
__launch_bounds__(1024)
__global__ void placeEmit(const float* __restrict__ props, const int* __restrict__ bidx,
                          const float* __restrict__ gtb, const int* __restrict__ glab,
                          const unsigned int* __restrict__ posBits,
                          const unsigned int* __restrict__ negBits,
                          const int* __restrict__ srkSeg, const int* __restrict__ fullSeg,
                          const int* __restrict__ offA, const int* __restrict__ needA,
                          const int* __restrict__ posNumArr, const int* __restrict__ slotEndArr,
                          float* __restrict__ out,
                          int P, int B, int G, int ITS, int NSEGP) {
    int blk = blockIdx.x;
    int seg = blk / ITS;
    int it = blk - seg * ITS;
    int type = it & 1;
    int i = it >> 1;

    __shared__ int s_srk[G_MAX], s_off[G_MAX], s_need[G_MAX];
    __shared__ int s_posNum;
    __shared__ unsigned int s_active;
    __shared__ int s_wcnt[16][G_MAX];

    int tid = threadIdx.x, lane = tid & 63, wid = tid >> 6;

    if (tid < G_MAX) {
        int srk = srkSeg[(size_t)(it * G_MAX + tid) * NSEGP + seg]
                + fullSeg[(size_t)it * NSEGP + seg];
        int nd = needA[it * G_MAX + tid];
        s_srk[tid] = srk;
        s_off[tid] = offA[it * G_MAX + tid];
        s_need[tid] = nd;
        unsigned long long bal = __ballot(srk < nd);
        if (tid == 0) {
            s_active = (unsigned int)bal;
            s_posNum = posNumArr[i];
        }
    }
    __syncthreads();

    // constant-fill the invalid tail (one designated block per image)
    if (type && seg == 0) {
        int slotEnd = slotEndArr[i];
        float* o_rois = out;
        float* o_del = out + (size_t)B * TRAIN_ROIS * 6;
        float* o_lab = o_del + (size_t)B * TRAIN_ROIS * 6;
        float* o_tag = o_lab + (size_t)B * TRAIN_ROIS;
        float* o_ridx = o_tag + (size_t)B * TRAIN_ROIS;
        for (int s = slotEnd + tid; s < TRAIN_ROIS; s += blockDim.x) {
            int row = i * TRAIN_ROIS + s;
#pragma unroll
            for (int k = 0; k < 6; ++k) {
                o_rois[row * 6 + k] = 0.0f;
                o_del[row * 6 + k] = 0.0f;
            }
            o_lab[row] = 0.0f;
            o_tag[row] = 0.0f;
            o_ridx[row] = -1.0f;
        }
    }

    unsigned int active = s_active;
    if (!active) return;
    int slotBase = type ? s_posNum : 0;

    int p = seg * SEG + tid;
    unsigned int mask = 0;
    if (p < P && bidx[p] == i)
        mask = (type ? negBits : posBits)[p] & active;

    // per-wave counts for active g's
    unsigned int am = active;
    while (am) {
        int g = __ffs(am) - 1; am &= am - 1;
        unsigned long long bal = __ballot((mask >> g) & 1u);
        if (lane == 0) s_wcnt[wid][g] = __popcll(bal);
    }
    __syncthreads();
    // exclusive prefix across the 16 waves (thread g handles bucket g)
    if (tid < G_MAX && ((active >> tid) & 1u)) {
        int run = 0;
#pragma unroll
        for (int w = 0; w < 16; ++w) {
            int c = s_wcnt[w][tid];
            s_wcnt[w][tid] = run;
            run += c;
        }
    }
    __syncthreads();
    // placement + direct output emit
    unsigned long long laneLt = (1ull << lane) - 1ull;
    am = active;
    while (am) {
        int g = __ffs(am) - 1; am &= am - 1;
        bool bit = (mask >> g) & 1u;
        unsigned long long bal = __ballot(bit);
        if (bit) {
            int r = s_srk[g] + s_wcnt[wid][g] + __popcll(bal & laneLt);
            if (r < s_need[g])
                emitRow(out, props, gtb, glab, i, slotBase + s_off[g] + r, p, g,
                        type == 0, B, G);
        }
    }
}

extern "C" void kernel_launch(void* const* d_in, const int* in_sizes, int n_in,
                              void* d_out, int out_size, void* d_ws, size_t ws_size,
                              hipStream_t stream) {
    const float* props = (const float*)d_in[0];
    const int* bidx = (const int*)d_in[1];
    const float* gtb = (const float*)d_in[2];
    const int* glab = (const int*)d_in[3];
    int P = in_sizes[1];                       // 65536
    int B = out_size / (TRAIN_ROIS * 15);      // 6+6+1+1+1 per slot -> 8
    int G = in_sizes[3] / B;                   // 32
    int ITS = B * 2;                           // 16
    int NSEG = (P + SEG - 1) / SEG;            // 64   (place segments)
    int NSEG4 = (P + SEG_A - 1) / SEG_A;       // 256  (phaseA quarters; =4*NSEG)
    int nSlots = ITS * G_MAX;                  // 512

    unsigned int* posBits = (unsigned int*)d_ws;            // [P]
    unsigned int* negBits = posBits + (size_t)P;            // [P]
    int* gcntSegT = (int*)(negBits + (size_t)P);            // [nSlots][NSEG4]
    int* gcntFullSegT = gcntSegT + (size_t)nSlots * NSEG4;  // [ITS][NSEG4]
    int* srkSeg = gcntFullSegT + (size_t)ITS * NSEG4;       // [nSlots][NSEG]
    int* fullSeg = srkSeg + (size_t)nSlots * NSEG;          // [ITS][NSEG]
    int* offA = fullSeg + (size_t)ITS * NSEG;               // [ITS][32]
    int* needA = offA + nSlots;                             // [ITS][32]
    int* posNumArr = needA + nSlots;                        // [B]
    int* slotEndArr = posNumArr + B;                        // [B]

    phaseA<<<NSEG4, SEG_A, 0, stream>>>(props, bidx, gtb, posBits, negBits,
                                        gcntSegT, gcntFullSegT, P, B, G, ITS, NSEG4);
    scanKernel<<<B, 512, 0, stream>>>(gcntSegT, gcntFullSegT, srkSeg, fullSeg,
                                      offA, needA, posNumArr, slotEndArr,
                                      B, G, NSEG4, NSEG);
    placeEmit<<<NSEG * ITS, SEG, 0, stream>>>(props, bidx, gtb, glab,
                                              posBits, negBits,
                                              srkSeg, fullSeg, offA, needA,
                                              posNumArr, slotEndArr,
                                              (float*)d_out, P, B, G, ITS, NSEG);
}